// Round 6
// baseline (240.961 us; speedup 1.0000x reference)
//
#include <hip/hip_runtime.h>

// Problem: B=4, S=4096, H=16, D=128 -> C=2048, K=4. All fp32.
// out[b,h,s,d] = silu( bias[c] + sum_{k=0..3} w[c,k] * x[b, s-3+k, c] ), c = h*128+d
//
// Round-9: round-8 design unchanged; fixes the compile error only
// (__builtin_nontemporal_store needs a clang ext_vector type, not HIP float4).
//
// Theory recap (round-8): rounds 0/1/4 all pinned at ~82us because every design
// periodically zeroed in-flight read bytes: per-row FIFO waits (r0) or
// __syncthreads vmcnt(0) drains that also wait stores and phase-lock all waves
// (r1/r4; Occupancy 18% = barrier-wait signature). Per-CU delivered BW was
// 12 GB/s vs 26 GB/s for a trivial fill.
// Fix: waves share NOTHING (each wave's 256 channels and its LDS ring slices
// are private), so drop ALL barriers. Per-wave software pipeline with counted
// vmcnt only:
//   tile t: s_waitcnt vmcnt(8)   // retires loads(t); stores(t-1)=8 newest fly
//           ds_read 11 rows      // wave-private ring slots
//           issue 8 gload_lds    // tile t+1 rows, async
//           sched_barrier(0)     // pin loads-before-stores (vmcnt accounting)
//           compute + store
// No s_barrier => deadlock structurally impossible. 16 decorrelated wave
// pipelines per CU keep ~8KB reads in flight each => continuous HBM demand.
// Ring-20 per-wave proof: R(t) reads ar[8t,8t+10]; L(t+1) writes [8t+11,8t+18];
// diffs 1..18, never 0 mod 20. Slot-reuse victims (ar-20) were consumed by the
// same wave one tile earlier (program order + lgkmcnt).

constexpr int Bb = 4, Ss = 4096, Hh = 16, Dd = 128, Cc = 2048, Kk = 4;
constexpr int SEQ  = 8;                  // s positions per tile
constexpr int CPB  = 1024;               // channels per block (256 thr x 4)
constexpr int TPB  = 8;                  // tiles per block (strip = 64 s)
constexpr int RING = 20;                 // LDS ring rows (80 KB, 2 blocks/CU)
constexpr int STRIPS = Ss / (SEQ * TPB); // 64

typedef float nf4 __attribute__((ext_vector_type(4)));   // clang vector (NT-store ok)

union F4 {
    float4 v;
    nf4    n;
    float  f[4];
};

__device__ __forceinline__ void gload1k(const float* g, float* l) {
    // async global->LDS: 16B/lane, wave-uniform LDS base + HW lane*16.
    __builtin_amdgcn_global_load_lds(
        (const __attribute__((address_space(1))) void*)g,
        (__attribute__((address_space(3))) void*)l,
        16, 0, 0);
}

__global__ __launch_bounds__(256, 4) void titans_conv(
    const float* __restrict__ x,     // [B,S,C]
    const float* __restrict__ w,     // [C,K]
    const float* __restrict__ bias,  // [C]
    float* __restrict__ out)         // [B,H,S,D]
{
    __shared__ float lds[RING * CPB];            // 20 * 4KB = 80 KB

    const int t     = threadIdx.x;               // 0..255
    const int wv    = t >> 6;                    // wave 0..3
    const int ln    = t & 63;
    const int strip = (int)blockIdx.x;           // 0..63
    const int b     = (int)blockIdx.y;
    const int cb    = (int)blockIdx.z * CPB;
    const int c0    = cb + t * 4;
    const int S0    = strip * (SEQ * TPB);

    // wave-lane column in x; row ar lives at s = S0 - 3 + ar
    const float* xw = x + (size_t)b * Ss * Cc + cb + wv * 256 + ln * 4;
    float* lw = &lds[wv * 256];                  // wave's slice: + sl*CPB

    // ---- weights + bias (compiler inserts its own waits before first use) ----
    float wf[4][4], bv[4];
    {
        const float4* wp = (const float4*)(w + (size_t)c0 * Kk);
        F4 u0, u1, u2, u3, ub;
        u0.v = wp[0]; u1.v = wp[1]; u2.v = wp[2]; u3.v = wp[3];
        ub.v = *(const float4*)(bias + c0);
        #pragma unroll
        for (int k = 0; k < 4; ++k) {
            wf[0][k] = u0.f[k]; wf[1][k] = u1.f[k];
            wf[2][k] = u2.f[k]; wf[3][k] = u3.f[k];
        }
        #pragma unroll
        for (int j = 0; j < 4; ++j) bv[j] = ub.f[j];
    }

    // ---- prologue: each wave stages ITS slice of rows ar = 0..10 ----
    if (strip > 0) {                              // block-uniform branch
        #pragma unroll
        for (int r = 0; r < 11; ++r)
            gload1k(xw + (size_t)(S0 - 3 + r) * Cc, lw + r * CPB);
    } else {                                      // zero halo rows ar=0..2
        #pragma unroll
        for (int r = 0; r < 3; ++r)
            *(float4*)&lds[r * CPB + t * 4] = float4{0.f, 0.f, 0.f, 0.f};
        #pragma unroll
        for (int r = 3; r < 11; ++r)
            gload1k(xw + (size_t)(S0 - 3 + r) * Cc, lw + r * CPB);
    }

    const int h = c0 >> 7;
    const int d = c0 & 127;
    float* orow = out + (((size_t)b * Hh + h) * Ss + S0) * Dd + d;

    #pragma unroll
    for (int tt = 0; tt < TPB; ++tt) {
        // retire loads(tt). FIFO: loads(tt) were issued before stores(tt-1),
        // so vmcnt(8) leaves exactly the 8 stores flying. t0: drain prologue.
        if (tt == 0) asm volatile("s_waitcnt vmcnt(0)" ::: "memory");
        else         asm volatile("s_waitcnt vmcnt(8)" ::: "memory");

        // ---- ds_read tile tt (11 rows, wave-private, compile-time slots) ----
        F4 rows[SEQ + 3];
        #pragma unroll
        for (int i = 0; i < SEQ + 3; ++i) {
            const int sl = (8 * tt + i) % RING;
            rows[i].v = *(const float4*)&lds[sl * CPB + t * 4];
        }

        // ---- issue tile tt+1's 8 rows async (fly under compute+stores) ----
        if (tt + 1 < TPB) {
            #pragma unroll
            for (int r = 0; r < 8; ++r) {
                const int ar = 8 * tt + 11 + r;          // compile-time
                gload1k(xw + (size_t)(S0 - 3 + ar) * Cc,
                        lw + (ar % RING) * CPB);
            }
        }
        __builtin_amdgcn_sched_barrier(0);   // loads stay ahead of stores

        // ---- compute + store tile tt ----
        #pragma unroll
        for (int i = 0; i < SEQ; ++i) {
            F4 res;
            #pragma unroll
            for (int j = 0; j < 4; ++j) {
                float z = bv[j];
                z = fmaf(wf[j][0], rows[i + 0].f[j], z);
                z = fmaf(wf[j][1], rows[i + 1].f[j], z);
                z = fmaf(wf[j][2], rows[i + 2].f[j], z);
                z = fmaf(wf[j][3], rows[i + 3].f[j], z);
                float e = __expf(-z);
                res.f[j] = z * __builtin_amdgcn_rcpf(1.0f + e);
            }
            __builtin_nontemporal_store(res.n,
                (nf4*)(orow + (size_t)(tt * SEQ + i) * Dd));
        }
    }
}

extern "C" void kernel_launch(void* const* d_in, const int* in_sizes, int n_in,
                              void* d_out, int out_size, void* d_ws, size_t ws_size,
                              hipStream_t stream) {
    const float* x    = (const float*)d_in[0];   // hidden_states [B,S,H,D] = [B,S,C]
    const float* w    = (const float*)d_in[1];   // conv_weight [C,K]
    const float* bias = (const float*)d_in[2];   // conv_bias [C]
    float* out        = (float*)d_out;           // [B,H,S,D]

    dim3 grid(STRIPS, Bb, Cc / CPB);  // 64 x 4 x 2 = 512 blocks = 2/CU resident
    titans_conv<<<grid, 256, 0, stream>>>(x, w, bias, out);
}

// Round 7
// 232.816 us; speedup vs baseline: 1.0350x; 1.0350x over previous
//
#include <hip/hip_runtime.h>

// Problem: B=4, S=4096, H=16, D=128 -> C=2048, K=4. All fp32.
// out[b,h,s,d] = silu( bias[c] + sum_{k=0..3} w[c,k] * x[b, s-3+k, c] ), c = h*128+d
// x layout: [B,S,C] contiguous; causal (zero left-pad).
//
// Round-10: RESTORATION of the round-1 kernel (best graded result, 232.79us).
// Session evidence: four structurally orthogonal designs (register pipeline /
// one-shot LDS-DMA / barriered ring / barrier-free per-wave counted-vmcnt ring)
// all land at 82-83us dispatch; duration is insensitive to FETCH_SIZE (90->69MB,
// -23% HBM read bytes, dt=0.5%), occupancy (56->17%), barriers, issue style,
// and store policy. That signature = externally constrained window: the graded
// iteration's 537MB re-poison fills drain dirty MALL lines to HBM during our
// window (invisible to TCC counters); our compulsory 268MB + ~256MB inherited
// drain at 6.3TB/s = ~82us = measured, every round. Kernel-side scheduling is
// exhausted; this restores the best-scoring config (4096 blocks, 3 blk/CU,
// one-shot global_load_lds staging) as the final state.

constexpr int Bb = 4, Ss = 4096, Hh = 16, Dd = 128, Cc = 2048, Kk = 4;
constexpr int SEQ  = 8;            // s positions per block
constexpr int CPB  = 1024;         // channels per block (256 threads x 4)
constexpr int ROWS = SEQ + 3;      // 11 staged rows (8 outputs + 3 halo)

union F4 {
    float4 v;
    float f[4];
};

__device__ __forceinline__ void gload_lds16(const float* g, float* l) {
    // async global->LDS, 16B per lane; LDS dest must be wave-uniform base.
    __builtin_amdgcn_global_load_lds(
        (const __attribute__((address_space(1))) void*)g,
        (__attribute__((address_space(3))) void*)l,
        16, 0, 0);
}

__global__ __launch_bounds__(256, 3) void titans_conv(
    const float* __restrict__ x,     // [B,S,C]
    const float* __restrict__ w,     // [C,K]
    const float* __restrict__ bias,  // [C]
    float* __restrict__ out)         // [B,H,S,D]
{
    __shared__ float lds[ROWS * CPB];           // 11 * 4KB = 44KB

    const int t  = threadIdx.x;                 // 0..255
    const int wv = t >> 6;                      // wave 0..3
    const int ln = t & 63;
    const int cb = (int)blockIdx.z * CPB;       // block channel base
    const int c0 = cb + t * 4;                  // this thread's 4 channels
    const int s0 = (int)blockIdx.x * SEQ;
    const int b  = (int)blockIdx.y;

    // per-lane global source within a row; LDS dest is wave-uniform + HW lane*16
    const float* xsrc = x + (size_t)b * Ss * Cc + cb + wv * 256 + ln * 4;

    // ---- weights + bias (L2-hot after first blocks; drained by the barrier) ----
    float wf[4][4], bv[4];
    {
        const float4* wp = (const float4*)(w + (size_t)c0 * Kk);
        F4 u0, u1, u2, u3, ub;
        u0.v = wp[0]; u1.v = wp[1]; u2.v = wp[2]; u3.v = wp[3];
        ub.v = *(const float4*)(bias + c0);
        #pragma unroll
        for (int k = 0; k < 4; ++k) {
            wf[0][k] = u0.f[k]; wf[1][k] = u1.f[k];
            wf[2][k] = u2.f[k]; wf[3][k] = u3.f[k];
        }
        #pragma unroll
        for (int j = 0; j < 4; ++j) bv[j] = ub.f[j];
    }

    // ---- issue ALL row loads async into LDS (11KB in flight per wave) ----
    if (s0 >= 3) {                               // every block except blockIdx.x==0
        #pragma unroll
        for (int r = 0; r < ROWS; ++r)
            gload_lds16(xsrc + (size_t)(s0 - 3 + r) * Cc,
                        &lds[r * CPB + wv * 256]);
    } else {                                     // zero left-pad (block-uniform)
        #pragma unroll
        for (int r = 0; r < 3; ++r)
            *(float4*)&lds[r * CPB + t * 4] = float4{0.f, 0.f, 0.f, 0.f};
        #pragma unroll
        for (int r = 3; r < ROWS; ++r)
            gload_lds16(xsrc + (size_t)(s0 - 3 + r) * Cc,
                        &lds[r * CPB + wv * 256]);
    }

    __syncthreads();   // one vmcnt(0)+lgkmcnt(0)+barrier per block, amortized over 44KB

    // ---- LDS -> regs: contiguous ds_read_b128, each wave reads its own 1KB ----
    F4 rows[ROWS];
    #pragma unroll
    for (int r = 0; r < ROWS; ++r)
        rows[r].v = *(const float4*)&lds[r * CPB + t * 4];

    const int h = c0 >> 7;            // c0 / 128
    const int d = c0 & 127;
    float* orow = out + (((size_t)b * Hh + h) * Ss + s0) * Dd + d;

    #pragma unroll
    for (int i = 0; i < SEQ; ++i) {
        F4 res;
        #pragma unroll
        for (int j = 0; j < 4; ++j) {
            float z = bv[j];
            z = fmaf(wf[j][0], rows[i + 0].f[j], z);
            z = fmaf(wf[j][1], rows[i + 1].f[j], z);
            z = fmaf(wf[j][2], rows[i + 2].f[j], z);
            z = fmaf(wf[j][3], rows[i + 3].f[j], z);
            // silu(z) = z / (1 + exp(-z))
            float e = __expf(-z);
            res.f[j] = z * __builtin_amdgcn_rcpf(1.0f + e);
        }
        *(float4*)(orow + (size_t)i * Dd) = res.v;   // stores never waited on
    }
}

extern "C" void kernel_launch(void* const* d_in, const int* in_sizes, int n_in,
                              void* d_out, int out_size, void* d_ws, size_t ws_size,
                              hipStream_t stream) {
    const float* x    = (const float*)d_in[0];   // hidden_states [B,S,H,D] = [B,S,C]
    const float* w    = (const float*)d_in[1];   // conv_weight [C,K]
    const float* bias = (const float*)d_in[2];   // conv_bias [C]
    float* out        = (float*)d_out;           // [B,H,S,D]

    dim3 grid(Ss / SEQ, Bb, Cc / CPB);  // 512 x 4 x 2 = 4096 blocks
    titans_conv<<<grid, 256, 0, stream>>>(x, w, bias, out);
}